// Round 9
// baseline (34828.833 us; speedup 1.0000x reference)
//
#include <hip/hip_runtime.h>

#define B 128
#define L 256
#define E 256
#define H 512
#define NBLK 256
#define NTHR 512

typedef float f4 __attribute__((ext_vector_type(4)));

// ---- ws float offsets ----
#define WS_CTX 0u          // [B][L][H] = 16777216 floats
#define WS_HT  18874368u   // [B][512] lstm h_t
#define WS_HH  18939904u   // [B][512] h carry
#define WS_XT  19136768u   // [B][256] current x
#define WS_FLG 19169536u   // flags region (uints): flags[0..255], gen at [320]

// ---- d_out float offsets ----
#define OUT_ALPHA 0u
#define OUT_PTR   8388608u
#define OUT_H     8421376u
#define OUT_C     8486912u

#define L2E 1.4426950408889634f

__device__ __forceinline__ float fast_rcp(float x) { return __builtin_amdgcn_rcpf(x); }

__device__ __forceinline__ float ftanh(float x) {
  float e = exp2f(x * (2.0f * L2E));
  return 1.0f - 2.0f * fast_rcp(e + 1.0f);
}
__device__ __forceinline__ float fsig(float x) {
  float e = exp2f(-x * L2E);
  return fast_rcp(1.0f + e);
}

// ==== batched coherent loads: N x dwordx4 + vmcnt(0) inside ONE asm block ====
#define CLD1(v0, p0)                                                          \
  asm volatile("global_load_dwordx4 %0, %1, off sc0 sc1\n\t"                  \
               "s_waitcnt vmcnt(0)"                                           \
               : "=&v"(v0) : "v"(p0) : "memory")

#define CLD6(va, pa)                                                          \
  asm volatile("global_load_dwordx4 %0, %6, off sc0 sc1\n\t"                  \
               "global_load_dwordx4 %1, %7, off sc0 sc1\n\t"                  \
               "global_load_dwordx4 %2, %8, off sc0 sc1\n\t"                  \
               "global_load_dwordx4 %3, %9, off sc0 sc1\n\t"                  \
               "global_load_dwordx4 %4, %10, off sc0 sc1\n\t"                 \
               "global_load_dwordx4 %5, %11, off sc0 sc1\n\t"                 \
               "s_waitcnt vmcnt(0)"                                           \
               : "=&v"(va[0]), "=&v"(va[1]), "=&v"(va[2]), "=&v"(va[3]),      \
                 "=&v"(va[4]), "=&v"(va[5])                                   \
               : "v"(pa[0]), "v"(pa[1]), "v"(pa[2]), "v"(pa[3]),              \
                 "v"(pa[4]), "v"(pa[5]) : "memory")

// ==== coherent packed stores (expcnt fence keeps data regs live) ====
#define CST4_1(p0, v0)                                                        \
  asm volatile("global_store_dwordx4 %0, %1, off sc0 sc1\n\t"                 \
               "s_waitcnt expcnt(0)"                                          \
               :: "v"(p0), "v"(v0) : "memory")

// ---- hierarchical barrier: flags -> block0 aggregates -> gen broadcast ----
__device__ __forceinline__ void gbar(unsigned* flags, unsigned tgt) {
  asm volatile("s_waitcnt vmcnt(0) lgkmcnt(0) expcnt(0)" ::: "memory");
  __syncthreads();
  if (threadIdx.x == 0) {
    unsigned* p = flags + blockIdx.x;
    asm volatile("global_store_dword %0, %1, off sc0 sc1" :: "v"(p), "v"(tgt) : "memory");
  }
  if (blockIdx.x == 0) {
    if (threadIdx.x < 64) {
      const unsigned* fp = flags + threadIdx.x * 4;
      for (;;) {
        unsigned f0, f1, f2, f3;
        asm volatile("global_load_dwordx4 v[20:23], %4, off sc0 sc1\n\t"
                     "s_waitcnt vmcnt(0)\n\t"
                     "v_mov_b32 %0, v20\n\t"
                     "v_mov_b32 %1, v21\n\t"
                     "v_mov_b32 %2, v22\n\t"
                     "v_mov_b32 %3, v23"
                     : "=v"(f0), "=v"(f1), "=v"(f2), "=v"(f3)
                     : "v"(fp) : "memory", "v20", "v21", "v22", "v23");
        bool ok = (f0 >= tgt) && (f1 >= tgt) && (f2 >= tgt) && (f3 >= tgt);
        if (__all(ok)) break;
        __builtin_amdgcn_s_sleep(1);
      }
    }
    __syncthreads();
    if (threadIdx.x == 0) {
      unsigned* gp = flags + 320;
      asm volatile("global_store_dword %0, %1, off sc0 sc1" :: "v"(gp), "v"(tgt) : "memory");
    }
  } else {
    if (threadIdx.x == 0) {
      const unsigned* gp = flags + 320;
      for (;;) {
        unsigned g;
        asm volatile("global_load_dword %0, %1, off sc0 sc1\n\ts_waitcnt vmcnt(0)"
                     : "=&v"(g) : "v"(gp) : "memory");
        if (g >= tgt) break;
        __builtin_amdgcn_s_sleep(4);
      }
    }
  }
  __syncthreads();
}

// ================= precompute ctx[b][l][g] (proven) =================
__global__ __launch_bounds__(256) void k_ctx(const float* __restrict__ context,
                                             const float* __restrict__ Wc,
                                             const float* __restrict__ bc,
                                             float* __restrict__ ws) {
  __shared__ float a_lds[64][33];
  __shared__ float b_lds[32][68];
  int t = threadIdx.x;
  int m0 = blockIdx.x * 64;
  int n0 = blockIdx.y * 64;
  int tx = t & 15, ty = t >> 4;
  float acc[4][4] = {};
  for (int kc = 0; kc < 16; ++kc) {
    int k0 = kc * 32;
    __syncthreads();
#pragma unroll
    for (int i = 0; i < 2; ++i) {
      int f40 = t + i * 256;
      int mm = f40 >> 3;
      int k4 = (f40 & 7) * 4;
      float4 v = *(const float4*)&context[(size_t)(m0 + mm) * H + k0 + k4];
      a_lds[mm][k4] = v.x; a_lds[mm][k4 + 1] = v.y; a_lds[mm][k4 + 2] = v.z; a_lds[mm][k4 + 3] = v.w;
    }
#pragma unroll
    for (int i = 0; i < 2; ++i) {
      int f40 = t + i * 256;
      int nn = f40 >> 3;
      int k4 = (f40 & 7) * 4;
      float4 v = *(const float4*)&Wc[(size_t)(n0 + nn) * H + k0 + k4];
      b_lds[k4][nn] = v.x; b_lds[k4 + 1][nn] = v.y; b_lds[k4 + 2][nn] = v.z; b_lds[k4 + 3][nn] = v.w;
    }
    __syncthreads();
#pragma unroll
    for (int kk = 0; kk < 32; ++kk) {
      float4 bv = *(const float4*)&b_lds[kk][tx * 4];
      float a0 = a_lds[ty * 4 + 0][kk], a1 = a_lds[ty * 4 + 1][kk];
      float a2 = a_lds[ty * 4 + 2][kk], a3 = a_lds[ty * 4 + 3][kk];
      acc[0][0] += a0 * bv.x; acc[0][1] += a0 * bv.y; acc[0][2] += a0 * bv.z; acc[0][3] += a0 * bv.w;
      acc[1][0] += a1 * bv.x; acc[1][1] += a1 * bv.y; acc[1][2] += a1 * bv.z; acc[1][3] += a1 * bv.w;
      acc[2][0] += a2 * bv.x; acc[2][1] += a2 * bv.y; acc[2][2] += a2 * bv.z; acc[2][3] += a2 * bv.w;
      acc[3][0] += a3 * bv.x; acc[3][1] += a3 * bv.y; acc[3][2] += a3 * bv.z; acc[3][3] += a3 * bv.w;
    }
  }
  float b0v = bc[n0 + tx * 4], b1v = bc[n0 + tx * 4 + 1], b2v = bc[n0 + tx * 4 + 2], b3v = bc[n0 + tx * 4 + 3];
#pragma unroll
  for (int i = 0; i < 4; ++i) {
    size_t o = WS_CTX + (size_t)(m0 + ty * 4 + i) * H + n0 + tx * 4;
    float4 v; v.x = acc[i][0] + b0v; v.y = acc[i][1] + b1v; v.z = acc[i][2] + b2v; v.w = acc[i][3] + b3v;
    *(float4*)&ws[o] = v;
  }
}

// ================= init: HH=dec_h, XT=dec_in, flags=0 =================
__global__ __launch_bounds__(256) void k_init(const float* __restrict__ dec_h,
                                              const float* __restrict__ dec_in,
                                              float* __restrict__ ws) {
  int flat = blockIdx.x * 256 + threadIdx.x;
  if (flat < 65536) {
    ws[WS_HH + flat] = dec_h[flat];
  } else if (flat < 98304) {
    ws[WS_XT + (flat - 65536)] = dec_in[flat - 65536];
  } else if (flat < 98816) {
    ((unsigned*)(ws + WS_FLG))[flat - 98304] = 0u;
  }
}

// ================= persistent fused decoder: 2 phases/step =================
__global__ __launch_bounds__(512, 1) void k_main(
    const float* __restrict__ Wi2h, const float* __restrict__ bi2h,
    const float* __restrict__ Wh2h, const float* __restrict__ bh2h,
    const float* __restrict__ Wout, const float* __restrict__ bout,
    const float* __restrict__ Winp, const float* __restrict__ binp,
    const float* __restrict__ Vv,   const float* __restrict__ emb,
    const float* __restrict__ dec_c,
    float* __restrict__ ws,         float* __restrict__ out) {
  __shared__ float s_act[13504];     // PG: acts[16][772] + gates[64][17] @12352
  __shared__ float s_maskP[256];
  __shared__ float s_mw[8], s_dw[8];
  __shared__ float s_red[4];
  __shared__ int   s_redi[4];
  __shared__ int   s_wc[4], s_wb[4];
  __shared__ int   s_mi, s_cnt;

  unsigned* flags = (unsigned*)(ws + WS_FLG);
  const int bid = blockIdx.x;
  const int t = threadIdx.x;
  const int wv = t >> 6, ln = t & 63;
  unsigned tgt = 0;

  float creg = 0.f;   // c-state: thread t<256 of PG block owns (u,b)

  if (bid < 128 && t < 256) s_maskP[t] = 1.0f;
  __syncthreads();

  for (int step = 0; step < L; ++step) {
    // ======== PG: gates + LSTM fused; XCD owns 4 j-tiles (weights L2-resident) ========
    {
      const int jt = (bid & 7) * 4 + ((bid >> 3) & 3);
      const int bt = bid >> 5;
      const int u0 = jt * 16, b0 = bt * 16;
      float* sact = s_act;            // [16][772]
      float* sg   = s_act + 12352;    // [64][17]
      f4 va[6]; const float* pa[6]; int sb[6], sq[6];
#pragma unroll
      for (int it = 0; it < 6; ++it) {
        unsigned c = (unsigned)(t + it * 512);
        int bl = (int)(c / 192u);
        int kq = (int)(c - (unsigned)bl * 192u);
        int kg = kq * 4;
        sb[it] = bl; sq[it] = kq;
        pa[it] = (kg < 256) ? ws + WS_XT + (size_t)(b0 + bl) * 256 + kg
                            : ws + WS_HH + (size_t)(b0 + bl) * 512 + (kg - 256);
      }
      CLD6(va, pa);
      __builtin_amdgcn_sched_barrier(0);
#pragma unroll
      for (int it = 0; it < 6; ++it) *(f4*)&sact[sb[it] * 772 + sq[it] * 4] = va[it];
      __syncthreads();

      const int jj = t >> 4, bb = t & 15;
      const int g = jj >> 3, up = (jj & 7) * 2;
      const int r0 = g * 512 + u0 + up;
      float a0 = 0.f, a1 = 0.f;
      {
        const float* w0 = Wi2h + (size_t)r0 * 256;
        const float* w1 = w0 + 256;
        const float* sa = sact + bb * 772;
#pragma unroll 8
        for (int k4 = 0; k4 < 64; ++k4) {
          float4 x = *(const float4*)&sa[k4 * 4];
          float4 p = *(const float4*)&w0[k4 * 4];
          float4 q = *(const float4*)&w1[k4 * 4];
          a0 += p.x * x.x + p.y * x.y + p.z * x.z + p.w * x.w;
          a1 += q.x * x.x + q.y * x.y + q.z * x.z + q.w * x.w;
        }
        const float* v0 = Wh2h + (size_t)r0 * 512;
        const float* v1 = v0 + 512;
        const float* shh = sa + 256;
#pragma unroll 8
        for (int k4 = 0; k4 < 128; ++k4) {
          float4 x = *(const float4*)&shh[k4 * 4];
          float4 p = *(const float4*)&v0[k4 * 4];
          float4 q = *(const float4*)&v1[k4 * 4];
          a0 += p.x * x.x + p.y * x.y + p.z * x.z + p.w * x.w;
          a1 += q.x * x.x + q.y * x.y + q.z * x.z + q.w * x.w;
        }
      }
      sg[(g * 16 + up) * 17 + bb]     = a0;
      sg[(g * 16 + up + 1) * 17 + bb] = a1;
      __syncthreads();
      if (t < 256) {
        const int uu = t >> 4, b2 = t & 15;
        const int j0 = u0 + uu;
        float si_ = sg[(     uu) * 17 + b2] + bi2h[       j0] + bh2h[       j0];
        float sf_ = sg[(16 + uu) * 17 + b2] + bi2h[ 512 + j0] + bh2h[ 512 + j0];
        float sg_ = sg[(32 + uu) * 17 + b2] + bi2h[1024 + j0] + bh2h[1024 + j0];
        float so_ = sg[(48 + uu) * 17 + b2] + bi2h[1536 + j0] + bh2h[1536 + j0];
        if (step == 0) creg = dec_c[(size_t)(b0 + b2) * 512 + j0];
        float cn = fsig(sf_) * creg + fsig(si_) * ftanh(sg_);
        creg = cn;
        float htv = fsig(so_) * ftanh(cn);
        s_act[b2 * 17 + uu] = htv;   // pack buffer [16b][16u+pad]
        if (step == L - 1) out[OUT_C + (size_t)(b0 + b2) * 512 + j0] = cn;
      }
      __syncthreads();
      if (t < 64) {
        const int b2 = t >> 2, q = t & 3;
        f4 hv;
        hv[0] = s_act[b2 * 17 + q * 4 + 0];
        hv[1] = s_act[b2 * 17 + q * 4 + 1];
        hv[2] = s_act[b2 * 17 + q * 4 + 2];
        hv[3] = s_act[b2 * 17 + q * 4 + 3];
        float* hp = ws + WS_HT + (size_t)(b0 + b2) * 512 + u0 + q * 4;
        CST4_1(hp, hv);
      }
    }
    ++tgt; gbar(flags, tgt);

    // ======== PA: inp + attention + h_new fused (blocks 0..127) ========
    if (bid < 128) {
      const int b = bid;
      float* s_inp  = s_act;                 // 512
      float* s_sc   = s_act + 512;           // 256
      int*   s_li   = (int*)(s_act + 768);   // 256
      float* s_hidp = s_act + 1024;          // 8*512
      float* s_out  = s_act + 5120;          // 512 (hid)
      float* s_ht   = s_act + 5632;          // 512
      float* s_hn   = s_act + 6144;          // 512 (h_new pack)
      if (t < 128) {
        f4 v;
        const float* p = ws + WS_HT + (size_t)b * 512 + t * 4;
        CLD1(v, p);
        *(f4*)&s_ht[t * 4] = v;
      }
      __syncthreads();
      // inp[t] = Winp[t,:] @ h_t[b] + binp[t]  (one g-row per thread; Winp L2-resident)
      {
        const float* w = Winp + (size_t)t * 512;
        float acc = 0.f;
#pragma unroll 8
        for (int k4 = 0; k4 < 128; ++k4) {
          float4 ww = *(const float4*)&w[k4 * 4];
          float4 xx = *(const float4*)&s_ht[k4 * 4];
          acc += ww.x * xx.x + ww.y * xx.y + ww.z * xx.z + ww.w * xx.w;
        }
        s_inp[t] = acc + binp[t];
      }
      __syncthreads();
      const int d0 = ln * 8;
      float inp8[8], v8[8];
#pragma unroll
      for (int i = 0; i < 8; ++i) { inp8[i] = s_inp[d0 + i]; v8[i] = Vv[d0 + i]; }
      bool validl = (t < 256) && (s_maskP[t] != 0.f);
      unsigned long long bal = __ballot(validl);
      if (t < 256 && (t & 63) == 0) s_wc[t >> 6] = (int)__popcll(bal);
      __syncthreads();
      if (t == 0) {
        int base = 0;
#pragma unroll
        for (int i = 0; i < 4; ++i) { s_wb[i] = base; base += s_wc[i]; }
        s_cnt = base;
      }
      __syncthreads();
      if (validl) {
        int idx = s_wb[t >> 6] + (int)__popcll(bal & ((1ull << (t & 63)) - 1ull));
        s_li[idx] = t;
      }
      __syncthreads();
      const int cnt = s_cnt;
      float m = -INFINITY, den = 0.f;
      float hid[8] = {0, 0, 0, 0, 0, 0, 0, 0};
      {
        int slot = wv;
        int l = 0; f4 c0 = {0, 0, 0, 0}, c1 = c0;
        if (slot < cnt) {
          l = s_li[slot];
          const f4* cp = (const f4*)(ws + WS_CTX + ((size_t)(b * 256 + l) * 512) + d0);
          c0 = __builtin_nontemporal_load(cp);
          c1 = __builtin_nontemporal_load(cp + 1);
        }
        while (slot < cnt) {
          const int nslot = slot + 8;
          int nl = 0; f4 n0 = {0, 0, 0, 0}, n1 = n0;
          if (nslot < cnt) {
            nl = s_li[nslot];
            const f4* np = (const f4*)(ws + WS_CTX + ((size_t)(b * 256 + nl) * 512) + d0);
            n0 = __builtin_nontemporal_load(np);
            n1 = __builtin_nontemporal_load(np + 1);
          }
          float part = v8[0] * ftanh(inp8[0] + c0[0]) + v8[1] * ftanh(inp8[1] + c0[1])
                     + v8[2] * ftanh(inp8[2] + c0[2]) + v8[3] * ftanh(inp8[3] + c0[3])
                     + v8[4] * ftanh(inp8[4] + c1[0]) + v8[5] * ftanh(inp8[5] + c1[1])
                     + v8[6] * ftanh(inp8[6] + c1[2]) + v8[7] * ftanh(inp8[7] + c1[3]);
#pragma unroll
          for (int off = 32; off > 0; off >>= 1) part += __shfl_xor(part, off);
          if (ln == 0) s_sc[l] = part;
          float mn = fmaxf(m, part);
          float scale = exp2f((m - mn) * L2E);
          float e = exp2f((part - mn) * L2E);
          den = den * scale + e;
          hid[0] = hid[0] * scale + e * c0[0]; hid[1] = hid[1] * scale + e * c0[1];
          hid[2] = hid[2] * scale + e * c0[2]; hid[3] = hid[3] * scale + e * c0[3];
          hid[4] = hid[4] * scale + e * c1[0]; hid[5] = hid[5] * scale + e * c1[1];
          hid[6] = hid[6] * scale + e * c1[2]; hid[7] = hid[7] * scale + e * c1[3];
          m = mn;
          c0 = n0; c1 = n1; l = nl; slot = nslot;
        }
      }
      if (ln == 0) { s_mw[wv] = m; s_dw[wv] = den; }
      __syncthreads();
      float M = s_mw[0];
#pragma unroll
      for (int w = 1; w < 8; ++w) M = fmaxf(M, s_mw[w]);
      float D = 0.f;
#pragma unroll
      for (int w = 0; w < 8; ++w) D += s_dw[w] * exp2f((s_mw[w] - M) * L2E);
      float fac = exp2f((m - M) * L2E);
#pragma unroll
      for (int i = 0; i < 8; ++i) s_hidp[wv * 512 + d0 + i] = hid[i] * fac;
      __syncthreads();
      const float rD = 1.0f / D;
      {
        float hs = 0.f;
#pragma unroll
        for (int w = 0; w < 8; ++w) hs += s_hidp[w * 512 + t];
        s_out[t] = hs * rD;
      }
      float sc = 0.f; bool valid = false;
      if (t < 256) {
        valid = (s_maskP[t] != 0.f);
        sc = s_sc[t];
        float alpha = valid ? exp2f((sc - M) * L2E) * rD : 0.f;
        out[OUT_ALPHA + ((size_t)b * 256 + step) * 256 + t] = alpha;
        float bs = valid ? sc : -INFINITY;
        int bi = t;
#pragma unroll
        for (int off = 32; off > 0; off >>= 1) {
          float os = __shfl_down(bs, off);
          int oi = __shfl_down(bi, off);
          if (os > bs || (os == bs && oi < bi)) { bs = os; bi = oi; }
        }
        if ((t & 63) == 0) { s_red[t >> 6] = bs; s_redi[t >> 6] = bi; }
      }
      __syncthreads();
      if (t == 0) {
        float mm = s_red[0]; int mi = s_redi[0];
#pragma unroll
        for (int w = 1; w < 4; ++w) {
          if (s_red[w] > mm || (s_red[w] == mm && s_redi[w] < mi)) { mm = s_red[w]; mi = s_redi[w]; }
        }
        s_mi = mi;
      }
      __syncthreads();
      const int mi = s_mi;
      // x gather + pointer/mask update
      if (t < 64) {
        float4 xv = *(const float4*)&emb[((size_t)b * 256 + mi) * 256 + t * 4];
        f4 xq; xq[0] = xv.x; xq[1] = xv.y; xq[2] = xv.z; xq[3] = xv.w;
        float* xp = ws + WS_XT + (size_t)b * 256 + t * 4;
        CST4_1(xp, xq);
      }
      if (t == 0) {
        out[OUT_PTR + (size_t)b * 256 + step] = (float)mi;
        s_maskP[mi] = 0.f;
      }
      // ---- h_new = tanh(Wout @ [hid; ht] + bout), 1 row/thread (Wout L2-resident) ----
      {
        const float* w = Wout + (size_t)t * 1024;
        float acc = 0.f;
#pragma unroll 8
        for (int k4 = 0; k4 < 128; ++k4) {
          float4 ww = *(const float4*)&w[k4 * 4];
          float4 xx = *(const float4*)&s_out[k4 * 4];
          acc += ww.x * xx.x + ww.y * xx.y + ww.z * xx.z + ww.w * xx.w;
        }
#pragma unroll 8
        for (int k4 = 0; k4 < 128; ++k4) {
          float4 ww = *(const float4*)&w[512 + k4 * 4];
          float4 xx = *(const float4*)&s_ht[k4 * 4];
          acc += ww.x * xx.x + ww.y * xx.y + ww.z * xx.z + ww.w * xx.w;
        }
        float h = ftanh(acc + bout[t]);
        s_hn[t] = h;
        if (step == L - 1) out[OUT_H + (size_t)b * 512 + t] = h;
      }
      __syncthreads();
      if (t < 128) {
        f4 hv = *(const f4*)&s_hn[t * 4];
        float* hp = ws + WS_HH + (size_t)b * 512 + t * 4;
        CST4_1(hp, hv);
      }
    }
    ++tgt; gbar(flags, tgt);
  }
}

extern "C" void kernel_launch(void* const* d_in, const int* in_sizes, int n_in,
                              void* d_out, int out_size, void* d_ws, size_t ws_size,
                              hipStream_t stream) {
  (void)in_sizes; (void)n_in; (void)out_size; (void)ws_size;
  const float* emb    = (const float*)d_in[0];
  const float* dec_in = (const float*)d_in[1];
  const float* dec_h  = (const float*)d_in[2];
  const float* dec_c  = (const float*)d_in[3];
  const float* ctx_in = (const float*)d_in[4];
  const float* W_i2h  = (const float*)d_in[5];
  const float* b_i2h  = (const float*)d_in[6];
  const float* W_h2h  = (const float*)d_in[7];
  const float* b_h2h  = (const float*)d_in[8];
  const float* W_out  = (const float*)d_in[9];
  const float* b_out  = (const float*)d_in[10];
  const float* W_inp  = (const float*)d_in[11];
  const float* b_inp  = (const float*)d_in[12];
  const float* W_ctx  = (const float*)d_in[13];
  const float* b_ctx  = (const float*)d_in[14];
  const float* Vv     = (const float*)d_in[15];
  float* out = (float*)d_out;
  float* ws  = (float*)d_ws;

  k_ctx<<<dim3(512, 8), 256, 0, stream>>>(ctx_in, W_ctx, b_ctx, ws);
  k_init<<<386, 256, 0, stream>>>(dec_h, dec_in, ws);
  k_main<<<NBLK, NTHR, 0, stream>>>(W_i2h, b_i2h, W_h2h, b_h2h, W_out, b_out,
                                    W_inp, b_inp, Vv, emb, dec_c, ws, out);
}

// Round 10
// 16529.338 us; speedup vs baseline: 2.1071x; 2.1071x over previous
//
#include <hip/hip_runtime.h>

#define B 128
#define L 256
#define E 256
#define H 512
#define NBLK 256
#define NTHR 512

typedef float f4 __attribute__((ext_vector_type(4)));

// ---- ws float offsets ----
#define WS_CTX 0u          // [B][L][H] = 16777216 floats
#define WS_HT  18874368u   // [B][512] lstm h_t
#define WS_HH  18939904u   // [B][512] h carry
#define WS_HID 19005440u   // [B][512] attn context
#define WS_INP 19071232u   // [B][512] attn query
#define WS_XT  19136768u   // [B][256] current x
#define WS_FLG 19169536u   // flags region (uints): blk flags [bid*16], genrep at 4096+k*16

// ---- d_out float offsets ----
#define OUT_ALPHA 0u
#define OUT_PTR   8388608u
#define OUT_H     8421376u
#define OUT_C     8486912u

#define L2E 1.4426950408889634f

__device__ __forceinline__ float fast_rcp(float x) { return __builtin_amdgcn_rcpf(x); }

__device__ __forceinline__ float ftanh(float x) {
  float e = exp2f(x * (2.0f * L2E));
  return 1.0f - 2.0f * fast_rcp(e + 1.0f);
}
__device__ __forceinline__ float fsig(float x) {
  float e = exp2f(-x * L2E);
  return fast_rcp(1.0f + e);
}

// ==== batched coherent loads: N x dwordx4 + vmcnt(0) inside ONE asm block ====
#define CLD1(v0, p0)                                                          \
  asm volatile("global_load_dwordx4 %0, %1, off sc0 sc1\n\t"                  \
               "s_waitcnt vmcnt(0)"                                           \
               : "=&v"(v0) : "v"(p0) : "memory")

#define CLD2(va, pa)                                                          \
  asm volatile("global_load_dwordx4 %0, %2, off sc0 sc1\n\t"                  \
               "global_load_dwordx4 %1, %3, off sc0 sc1\n\t"                  \
               "s_waitcnt vmcnt(0)"                                           \
               : "=&v"(va[0]), "=&v"(va[1])                                   \
               : "v"(pa[0]), "v"(pa[1]) : "memory")

#define CLD4(va, pa)                                                          \
  asm volatile("global_load_dwordx4 %0, %4, off sc0 sc1\n\t"                  \
               "global_load_dwordx4 %1, %5, off sc0 sc1\n\t"                  \
               "global_load_dwordx4 %2, %6, off sc0 sc1\n\t"                  \
               "global_load_dwordx4 %3, %7, off sc0 sc1\n\t"                  \
               "s_waitcnt vmcnt(0)"                                           \
               : "=&v"(va[0]), "=&v"(va[1]), "=&v"(va[2]), "=&v"(va[3])       \
               : "v"(pa[0]), "v"(pa[1]), "v"(pa[2]), "v"(pa[3]) : "memory")

#define CLD6(va, pa)                                                          \
  asm volatile("global_load_dwordx4 %0, %6, off sc0 sc1\n\t"                  \
               "global_load_dwordx4 %1, %7, off sc0 sc1\n\t"                  \
               "global_load_dwordx4 %2, %8, off sc0 sc1\n\t"                  \
               "global_load_dwordx4 %3, %9, off sc0 sc1\n\t"                  \
               "global_load_dwordx4 %4, %10, off sc0 sc1\n\t"                 \
               "global_load_dwordx4 %5, %11, off sc0 sc1\n\t"                 \
               "s_waitcnt vmcnt(0)"                                           \
               : "=&v"(va[0]), "=&v"(va[1]), "=&v"(va[2]), "=&v"(va[3]),      \
                 "=&v"(va[4]), "=&v"(va[5])                                   \
               : "v"(pa[0]), "v"(pa[1]), "v"(pa[2]), "v"(pa[3]),              \
                 "v"(pa[4]), "v"(pa[5]) : "memory")

// ==== coherent packed stores (expcnt fence keeps data regs live) ====
#define CST4_1(p0, v0)                                                        \
  asm volatile("global_store_dwordx4 %0, %1, off sc0 sc1\n\t"                 \
               "s_waitcnt expcnt(0)"                                          \
               :: "v"(p0), "v"(v0) : "memory")

// ---- barrier: 64B-strided flags; block0 aggregates; gen replicated x8 ----
__device__ __forceinline__ void gbar(unsigned* flags, unsigned tgt) {
  asm volatile("s_waitcnt vmcnt(0) lgkmcnt(0) expcnt(0)" ::: "memory");
  __syncthreads();
  if (threadIdx.x == 0) {
    unsigned* p = flags + blockIdx.x * 16;
    asm volatile("global_store_dword %0, %1, off sc0 sc1" :: "v"(p), "v"(tgt) : "memory");
  }
  if (blockIdx.x == 0) {
    if (threadIdx.x < 64) {
      const unsigned* p0 = flags + (threadIdx.x * 4 + 0) * 16;
      const unsigned* p1 = flags + (threadIdx.x * 4 + 1) * 16;
      const unsigned* p2 = flags + (threadIdx.x * 4 + 2) * 16;
      const unsigned* p3 = flags + (threadIdx.x * 4 + 3) * 16;
      for (;;) {
        unsigned f0, f1, f2, f3;
        asm volatile("global_load_dword %0, %4, off sc0 sc1\n\t"
                     "global_load_dword %1, %5, off sc0 sc1\n\t"
                     "global_load_dword %2, %6, off sc0 sc1\n\t"
                     "global_load_dword %3, %7, off sc0 sc1\n\t"
                     "s_waitcnt vmcnt(0)"
                     : "=&v"(f0), "=&v"(f1), "=&v"(f2), "=&v"(f3)
                     : "v"(p0), "v"(p1), "v"(p2), "v"(p3) : "memory");
        if (__all(f0 >= tgt && f1 >= tgt && f2 >= tgt && f3 >= tgt)) break;
        __builtin_amdgcn_s_sleep(1);
      }
    }
    __syncthreads();
    if (threadIdx.x < 8) {
      unsigned* gp = flags + 4096 + threadIdx.x * 16;
      asm volatile("global_store_dword %0, %1, off sc0 sc1" :: "v"(gp), "v"(tgt) : "memory");
    }
  } else {
    if (threadIdx.x == 0) {
      const unsigned* gp = flags + 4096 + (blockIdx.x & 7) * 16;
      for (;;) {
        unsigned g;
        asm volatile("global_load_dword %0, %1, off sc0 sc1\n\ts_waitcnt vmcnt(0)"
                     : "=&v"(g) : "v"(gp) : "memory");
        if (g >= tgt) break;
        __builtin_amdgcn_s_sleep(2);
      }
    }
  }
  __syncthreads();
}

// ================= precompute ctx[b][l][g] (proven) =================
__global__ __launch_bounds__(256) void k_ctx(const float* __restrict__ context,
                                             const float* __restrict__ Wc,
                                             const float* __restrict__ bc,
                                             float* __restrict__ ws) {
  __shared__ float a_lds[64][33];
  __shared__ float b_lds[32][68];
  int t = threadIdx.x;
  int m0 = blockIdx.x * 64;
  int n0 = blockIdx.y * 64;
  int tx = t & 15, ty = t >> 4;
  float acc[4][4] = {};
  for (int kc = 0; kc < 16; ++kc) {
    int k0 = kc * 32;
    __syncthreads();
#pragma unroll
    for (int i = 0; i < 2; ++i) {
      int f40 = t + i * 256;
      int mm = f40 >> 3;
      int k4 = (f40 & 7) * 4;
      float4 v = *(const float4*)&context[(size_t)(m0 + mm) * H + k0 + k4];
      a_lds[mm][k4] = v.x; a_lds[mm][k4 + 1] = v.y; a_lds[mm][k4 + 2] = v.z; a_lds[mm][k4 + 3] = v.w;
    }
#pragma unroll
    for (int i = 0; i < 2; ++i) {
      int f40 = t + i * 256;
      int nn = f40 >> 3;
      int k4 = (f40 & 7) * 4;
      float4 v = *(const float4*)&Wc[(size_t)(n0 + nn) * H + k0 + k4];
      b_lds[k4][nn] = v.x; b_lds[k4 + 1][nn] = v.y; b_lds[k4 + 2][nn] = v.z; b_lds[k4 + 3][nn] = v.w;
    }
    __syncthreads();
#pragma unroll
    for (int kk = 0; kk < 32; ++kk) {
      float4 bv = *(const float4*)&b_lds[kk][tx * 4];
      float a0 = a_lds[ty * 4 + 0][kk], a1 = a_lds[ty * 4 + 1][kk];
      float a2 = a_lds[ty * 4 + 2][kk], a3 = a_lds[ty * 4 + 3][kk];
      acc[0][0] += a0 * bv.x; acc[0][1] += a0 * bv.y; acc[0][2] += a0 * bv.z; acc[0][3] += a0 * bv.w;
      acc[1][0] += a1 * bv.x; acc[1][1] += a1 * bv.y; acc[1][2] += a1 * bv.z; acc[1][3] += a1 * bv.w;
      acc[2][0] += a2 * bv.x; acc[2][1] += a2 * bv.y; acc[2][2] += a2 * bv.z; acc[2][3] += a2 * bv.w;
      acc[3][0] += a3 * bv.x; acc[3][1] += a3 * bv.y; acc[3][2] += a3 * bv.z; acc[3][3] += a3 * bv.w;
    }
  }
  float b0v = bc[n0 + tx * 4], b1v = bc[n0 + tx * 4 + 1], b2v = bc[n0 + tx * 4 + 2], b3v = bc[n0 + tx * 4 + 3];
#pragma unroll
  for (int i = 0; i < 4; ++i) {
    size_t o = WS_CTX + (size_t)(m0 + ty * 4 + i) * H + n0 + tx * 4;
    float4 v; v.x = acc[i][0] + b0v; v.y = acc[i][1] + b1v; v.z = acc[i][2] + b2v; v.w = acc[i][3] + b3v;
    *(float4*)&ws[o] = v;
  }
}

// ================= init: HH=dec_h, XT=dec_in, flags=0 =================
__global__ __launch_bounds__(256) void k_init(const float* __restrict__ dec_h,
                                              const float* __restrict__ dec_in,
                                              float* __restrict__ ws) {
  int flat = blockIdx.x * 256 + threadIdx.x;
  if (flat < 65536) {
    ws[WS_HH + flat] = dec_h[flat];
  } else if (flat < 98304) {
    ws[WS_XT + (flat - 65536)] = dec_in[flat - 65536];
  } else if (flat < 102528) {
    ((unsigned*)(ws + WS_FLG))[flat - 98304] = 0u;
  }
}

// ================= persistent fused decoder: 4 phases, XCD-pinned weights =================
__global__ __launch_bounds__(512, 1) void k_main(
    const float* __restrict__ Wi2h, const float* __restrict__ bi2h,
    const float* __restrict__ Wh2h, const float* __restrict__ bh2h,
    const float* __restrict__ Wout, const float* __restrict__ bout,
    const float* __restrict__ Winp, const float* __restrict__ binp,
    const float* __restrict__ Vv,   const float* __restrict__ emb,
    const float* __restrict__ dec_c,
    float* __restrict__ ws,         float* __restrict__ out) {
  __shared__ float s_act[13504];     // PG: acts[16][772] + gates[64][17] @12352
  __shared__ float s_maskP[256];
  __shared__ float s_mw[8], s_dw[8];
  __shared__ float s_red[4];
  __shared__ int   s_redi[4];
  __shared__ int   s_wc[4], s_wb[4];
  __shared__ int   s_mi, s_cnt;

  unsigned* flags = (unsigned*)(ws + WS_FLG);
  const int bid = blockIdx.x;
  const int t = threadIdx.x;
  const int wv = t >> 6, ln = t & 63;
  unsigned tgt = 0;

  float creg = 0.f;   // c-state: thread t<256 of PG block owns (u,b)

  if (bid < 128 && t < 256) s_maskP[t] = 1.0f;
  __syncthreads();

  for (int step = 0; step < L; ++step) {
    // ======== PG: gates + LSTM fused; XCD owns 4 j-tiles (weights L2-resident) ========
    {
      const int jt = (bid & 7) * 4 + ((bid >> 3) & 3);
      const int bt = bid >> 5;
      const int u0 = jt * 16, b0 = bt * 16;
      float* sact = s_act;            // [16][772]
      float* sg   = s_act + 12352;    // [64][17]
      f4 va[6]; const float* pa[6]; int sb[6], sq[6];
#pragma unroll
      for (int it = 0; it < 6; ++it) {
        unsigned c = (unsigned)(t + it * 512);
        int bl = (int)(c / 192u);
        int kq = (int)(c - (unsigned)bl * 192u);
        int kg = kq * 4;
        sb[it] = bl; sq[it] = kq;
        pa[it] = (kg < 256) ? ws + WS_XT + (size_t)(b0 + bl) * 256 + kg
                            : ws + WS_HH + (size_t)(b0 + bl) * 512 + (kg - 256);
      }
      CLD6(va, pa);
      __builtin_amdgcn_sched_barrier(0);
#pragma unroll
      for (int it = 0; it < 6; ++it) *(f4*)&sact[sb[it] * 772 + sq[it] * 4] = va[it];
      __syncthreads();

      const int jj = t >> 4, bb = t & 15;
      const int g = jj >> 3, up = (jj & 7) * 2;
      const int r0 = g * 512 + u0 + up;
      float a0 = 0.f, a1 = 0.f;
      {
        const float* w0 = Wi2h + (size_t)r0 * 256;
        const float* w1 = w0 + 256;
        const float* sa = sact + bb * 772;
#pragma unroll 8
        for (int k4 = 0; k4 < 64; ++k4) {
          float4 x = *(const float4*)&sa[k4 * 4];
          float4 p = *(const float4*)&w0[k4 * 4];
          float4 q = *(const float4*)&w1[k4 * 4];
          a0 += p.x * x.x + p.y * x.y + p.z * x.z + p.w * x.w;
          a1 += q.x * x.x + q.y * x.y + q.z * x.z + q.w * x.w;
        }
        const float* v0 = Wh2h + (size_t)r0 * 512;
        const float* v1 = v0 + 512;
        const float* shh = sa + 256;
#pragma unroll 8
        for (int k4 = 0; k4 < 128; ++k4) {
          float4 x = *(const float4*)&shh[k4 * 4];
          float4 p = *(const float4*)&v0[k4 * 4];
          float4 q = *(const float4*)&v1[k4 * 4];
          a0 += p.x * x.x + p.y * x.y + p.z * x.z + p.w * x.w;
          a1 += q.x * x.x + q.y * x.y + q.z * x.z + q.w * x.w;
        }
      }
      sg[(g * 16 + up) * 17 + bb]     = a0;
      sg[(g * 16 + up + 1) * 17 + bb] = a1;
      __syncthreads();
      if (t < 256) {
        const int uu = t >> 4, b2 = t & 15;
        const int j0 = u0 + uu;
        float si_ = sg[(     uu) * 17 + b2] + bi2h[       j0] + bh2h[       j0];
        float sf_ = sg[(16 + uu) * 17 + b2] + bi2h[ 512 + j0] + bh2h[ 512 + j0];
        float sg_ = sg[(32 + uu) * 17 + b2] + bi2h[1024 + j0] + bh2h[1024 + j0];
        float so_ = sg[(48 + uu) * 17 + b2] + bi2h[1536 + j0] + bh2h[1536 + j0];
        if (step == 0) creg = dec_c[(size_t)(b0 + b2) * 512 + j0];
        float cn = fsig(sf_) * creg + fsig(si_) * ftanh(sg_);
        creg = cn;
        float htv = fsig(so_) * ftanh(cn);
        s_act[b2 * 17 + uu] = htv;   // pack buffer [16b][16u+pad]
        if (step == L - 1) out[OUT_C + (size_t)(b0 + b2) * 512 + j0] = cn;
      }
      __syncthreads();
      if (t < 64) {
        const int b2 = t >> 2, q = t & 3;
        f4 hv;
        hv[0] = s_act[b2 * 17 + q * 4 + 0];
        hv[1] = s_act[b2 * 17 + q * 4 + 1];
        hv[2] = s_act[b2 * 17 + q * 4 + 2];
        hv[3] = s_act[b2 * 17 + q * 4 + 3];
        float* hp = ws + WS_HT + (size_t)(b0 + b2) * 512 + u0 + q * 4;
        CST4_1(hp, hv);
      }
    }
    ++tgt; gbar(flags, tgt);

    // ======== PI: inp = Winp@h_t + binp; XCD owns 2 g-tiles; 16 b-tiles(8) ========
    {
      const int gt = (bid & 7) * 2 + ((bid >> 3) & 1);
      const int bt = bid >> 4;
      const int g0 = gt * 32, b0 = bt * 8;
      float* si = s_act;               // [8][516]
      float* stmp = s_act + 4128;      // [8][33]
      f4 va[2]; const float* pa[2];
#pragma unroll
      for (int it = 0; it < 2; ++it) {
        int c = t + it * 512;
        int bl = c >> 7, kq = c & 127;
        pa[it] = ws + WS_HT + (size_t)(b0 + bl) * 512 + kq * 4;
      }
      CLD2(va, pa);
      __builtin_amdgcn_sched_barrier(0);
#pragma unroll
      for (int it = 0; it < 2; ++it) {
        int c = t + it * 512;
        int bl = c >> 7, kq = c & 127;
        *(f4*)&si[bl * 516 + kq * 4] = va[it];
      }
      __syncthreads();
      if (t < 256) {
        const int gl = t >> 3, bb = t & 7;
        const float* w = Winp + (size_t)(g0 + gl) * 512;
        const float* sa = si + bb * 516;
        float acc = 0.f;
#pragma unroll 8
        for (int k4 = 0; k4 < 128; ++k4) {
          float4 ww = *(const float4*)&w[k4 * 4];
          float4 xx = *(const float4*)&sa[k4 * 4];
          acc += ww.x * xx.x + ww.y * xx.y + ww.z * xx.z + ww.w * xx.w;
        }
        stmp[bb * 33 + gl] = acc + binp[g0 + gl];
      }
      __syncthreads();
      if (t < 64) {
        const int bb = t >> 3, q = t & 7;
        f4 v;
        v[0] = stmp[bb * 33 + q * 4 + 0];
        v[1] = stmp[bb * 33 + q * 4 + 1];
        v[2] = stmp[bb * 33 + q * 4 + 2];
        v[3] = stmp[bb * 33 + q * 4 + 3];
        float* p = ws + WS_INP + (size_t)(b0 + bb) * 512 + g0 + q * 4;
        CST4_1(p, v);
      }
    }
    ++tgt; gbar(flags, tgt);

    // ======== PA: attention (blocks 0..127), 4-slot pipelined nt ctx pass ========
    if (bid < 128) {
      const int b = bid;
      float* s_inp  = s_act;                 // 512
      float* s_sc   = s_act + 512;           // 256
      int*   s_li   = (int*)(s_act + 768);   // 256
      float* s_hidp = s_act + 1024;          // 8*512
      float* s_out  = s_act + 5120;          // 512
      if (t < 128) {
        f4 v;
        const float* p = ws + WS_INP + (size_t)b * 512 + t * 4;
        CLD1(v, p);
        *(f4*)&s_inp[t * 4] = v;
      }
      __syncthreads();
      const int d0 = ln * 8;
      float inp8[8], v8[8];
#pragma unroll
      for (int i = 0; i < 8; ++i) { inp8[i] = s_inp[d0 + i]; v8[i] = Vv[d0 + i]; }
      bool validl = (t < 256) && (s_maskP[t] != 0.f);
      unsigned long long bal = __ballot(validl);
      if (t < 256 && (t & 63) == 0) s_wc[t >> 6] = (int)__popcll(bal);
      __syncthreads();
      if (t == 0) {
        int base = 0;
#pragma unroll
        for (int i = 0; i < 4; ++i) { s_wb[i] = base; base += s_wc[i]; }
        s_cnt = base;
      }
      __syncthreads();
      if (validl) {
        int idx = s_wb[t >> 6] + (int)__popcll(bal & ((1ull << (t & 63)) - 1ull));
        s_li[idx] = t;
      }
      __syncthreads();
      const int cnt = s_cnt;
      float m = -INFINITY, den = 0.f;
      float hid[8] = {0, 0, 0, 0, 0, 0, 0, 0};
      {
        f4 cur0a, cur0b, cur1a, cur1b, cur2a, cur2b, cur3a, cur3b;
        int l0i, l1i, l2i, l3i;
        int base = wv * 4;
        {
          int s0 = base, s1 = base + 1, s2 = base + 2, s3 = base + 3;
          int a = (s0 < cnt) ? s_li[s0] : 0;  l0i = (s0 < cnt) ? a : -1;
          int bb2 = (s1 < cnt) ? s_li[s1] : 0; l1i = (s1 < cnt) ? bb2 : -1;
          int c = (s2 < cnt) ? s_li[s2] : 0;  l2i = (s2 < cnt) ? c : -1;
          int d = (s3 < cnt) ? s_li[s3] : 0;  l3i = (s3 < cnt) ? d : -1;
          const f4* p0 = (const f4*)(ws + WS_CTX + ((size_t)(b * 256 + a) * 512) + d0);
          const f4* p1 = (const f4*)(ws + WS_CTX + ((size_t)(b * 256 + bb2) * 512) + d0);
          const f4* p2 = (const f4*)(ws + WS_CTX + ((size_t)(b * 256 + c) * 512) + d0);
          const f4* p3 = (const f4*)(ws + WS_CTX + ((size_t)(b * 256 + d) * 512) + d0);
          cur0a = __builtin_nontemporal_load(p0); cur0b = __builtin_nontemporal_load(p0 + 1);
          cur1a = __builtin_nontemporal_load(p1); cur1b = __builtin_nontemporal_load(p1 + 1);
          cur2a = __builtin_nontemporal_load(p2); cur2b = __builtin_nontemporal_load(p2 + 1);
          cur3a = __builtin_nontemporal_load(p3); cur3b = __builtin_nontemporal_load(p3 + 1);
        }
        for (; base < cnt; base += 32) {
          // prefetch next quad
          f4 n0a, n0b, n1a, n1b, n2a, n2b, n3a, n3b;
          int nl0, nl1, nl2, nl3;
          {
            int s0 = base + 32, s1 = base + 33, s2 = base + 34, s3 = base + 35;
            int a = (s0 < cnt) ? s_li[s0] : 0;  nl0 = (s0 < cnt) ? a : -1;
            int bb2 = (s1 < cnt) ? s_li[s1] : 0; nl1 = (s1 < cnt) ? bb2 : -1;
            int c = (s2 < cnt) ? s_li[s2] : 0;  nl2 = (s2 < cnt) ? c : -1;
            int d = (s3 < cnt) ? s_li[s3] : 0;  nl3 = (s3 < cnt) ? d : -1;
            const f4* p0 = (const f4*)(ws + WS_CTX + ((size_t)(b * 256 + a) * 512) + d0);
            const f4* p1 = (const f4*)(ws + WS_CTX + ((size_t)(b * 256 + bb2) * 512) + d0);
            const f4* p2 = (const f4*)(ws + WS_CTX + ((size_t)(b * 256 + c) * 512) + d0);
            const f4* p3 = (const f4*)(ws + WS_CTX + ((size_t)(b * 256 + d) * 512) + d0);
            n0a = __builtin_nontemporal_load(p0); n0b = __builtin_nontemporal_load(p0 + 1);
            n1a = __builtin_nontemporal_load(p1); n1b = __builtin_nontemporal_load(p1 + 1);
            n2a = __builtin_nontemporal_load(p2); n2b = __builtin_nontemporal_load(p2 + 1);
            n3a = __builtin_nontemporal_load(p3); n3b = __builtin_nontemporal_load(p3 + 1);
          }
          // compute 4 slots
          float sv0, sv1, sv2, sv3;
          {
            float part = v8[0] * ftanh(inp8[0] + cur0a[0]) + v8[1] * ftanh(inp8[1] + cur0a[1])
                       + v8[2] * ftanh(inp8[2] + cur0a[2]) + v8[3] * ftanh(inp8[3] + cur0a[3])
                       + v8[4] * ftanh(inp8[4] + cur0b[0]) + v8[5] * ftanh(inp8[5] + cur0b[1])
                       + v8[6] * ftanh(inp8[6] + cur0b[2]) + v8[7] * ftanh(inp8[7] + cur0b[3]);
#pragma unroll
            for (int off = 32; off > 0; off >>= 1) part += __shfl_xor(part, off);
            if (l0i >= 0 && ln == 0) s_sc[l0i] = part;
            sv0 = (l0i >= 0) ? part : -INFINITY;
          }
          {
            float part = v8[0] * ftanh(inp8[0] + cur1a[0]) + v8[1] * ftanh(inp8[1] + cur1a[1])
                       + v8[2] * ftanh(inp8[2] + cur1a[2]) + v8[3] * ftanh(inp8[3] + cur1a[3])
                       + v8[4] * ftanh(inp8[4] + cur1b[0]) + v8[5] * ftanh(inp8[5] + cur1b[1])
                       + v8[6] * ftanh(inp8[6] + cur1b[2]) + v8[7] * ftanh(inp8[7] + cur1b[3]);
#pragma unroll
            for (int off = 32; off > 0; off >>= 1) part += __shfl_xor(part, off);
            if (l1i >= 0 && ln == 0) s_sc[l1i] = part;
            sv1 = (l1i >= 0) ? part : -INFINITY;
          }
          {
            float part = v8[0] * ftanh(inp8[0] + cur2a[0]) + v8[1] * ftanh(inp8[1] + cur2a[1])
                       + v8[2] * ftanh(inp8[2] + cur2a[2]) + v8[3] * ftanh(inp8[3] + cur2a[3])
                       + v8[4] * ftanh(inp8[4] + cur2b[0]) + v8[5] * ftanh(inp8[5] + cur2b[1])
                       + v8[6] * ftanh(inp8[6] + cur2b[2]) + v8[7] * ftanh(inp8[7] + cur2b[3]);
#pragma unroll
            for (int off = 32; off > 0; off >>= 1) part += __shfl_xor(part, off);
            if (l2i >= 0 && ln == 0) s_sc[l2i] = part;
            sv2 = (l2i >= 0) ? part : -INFINITY;
          }
          {
            float part = v8[0] * ftanh(inp8[0] + cur3a[0]) + v8[1] * ftanh(inp8[1] + cur3a[1])
                       + v8[2] * ftanh(inp8[2] + cur3a[2]) + v8[3] * ftanh(inp8[3] + cur3a[3])
                       + v8[4] * ftanh(inp8[4] + cur3b[0]) + v8[5] * ftanh(inp8[5] + cur3b[1])
                       + v8[6] * ftanh(inp8[6] + cur3b[2]) + v8[7] * ftanh(inp8[7] + cur3b[3]);
#pragma unroll
            for (int off = 32; off > 0; off >>= 1) part += __shfl_xor(part, off);
            if (l3i >= 0 && ln == 0) s_sc[l3i] = part;
            sv3 = (l3i >= 0) ? part : -INFINITY;
          }
          float mn = fmaxf(m, fmaxf(fmaxf(sv0, sv1), fmaxf(sv2, sv3)));
          float scale = exp2f((m - mn) * L2E);
          float e0 = exp2f((sv0 - mn) * L2E);
          float e1 = exp2f((sv1 - mn) * L2E);
          float e2 = exp2f((sv2 - mn) * L2E);
          float e3 = exp2f((sv3 - mn) * L2E);
          den = den * scale + ((e0 + e1) + (e2 + e3));
          hid[0] = hid[0] * scale + e0 * cur0a[0] + e1 * cur1a[0] + e2 * cur2a[0] + e3 * cur3a[0];
          hid[1] = hid[1] * scale + e0 * cur0a[1] + e1 * cur1a[1] + e2 * cur2a[1] + e3 * cur3a[1];
          hid[2] = hid[2] * scale + e0 * cur0a[2] + e1 * cur1a[2] + e2 * cur2a[2] + e3 * cur3a[2];
          hid[3] = hid[3] * scale + e0 * cur0a[3] + e1 * cur1a[3] + e2 * cur2a[3] + e3 * cur3a[3];
          hid[4] = hid[4] * scale + e0 * cur0b[0] + e1 * cur1b[0] + e2 * cur2b[0] + e3 * cur3b[0];
          hid[5] = hid[5] * scale + e0 * cur0b[1] + e1 * cur1b[1] + e2 * cur2b[1] + e3 * cur3b[1];
          hid[6] = hid[6] * scale + e0 * cur0b[2] + e1 * cur1b[2] + e2 * cur2b[2] + e3 * cur3b[2];
          hid[7] = hid[7] * scale + e0 * cur0b[3] + e1 * cur1b[3] + e2 * cur2b[3] + e3 * cur3b[3];
          m = mn;
          cur0a = n0a; cur0b = n0b; cur1a = n1a; cur1b = n1b;
          cur2a = n2a; cur2b = n2b; cur3a = n3a; cur3b = n3b;
          l0i = nl0; l1i = nl1; l2i = nl2; l3i = nl3;
        }
      }
      if (ln == 0) { s_mw[wv] = m; s_dw[wv] = den; }
      __syncthreads();
      float M = s_mw[0];
#pragma unroll
      for (int w = 1; w < 8; ++w) M = fmaxf(M, s_mw[w]);
      float D = 0.f;
#pragma unroll
      for (int w = 0; w < 8; ++w) D += s_dw[w] * exp2f((s_mw[w] - M) * L2E);
      float fac = exp2f((m - M) * L2E);
#pragma unroll
      for (int i = 0; i < 8; ++i) s_hidp[wv * 512 + d0 + i] = hid[i] * fac;
      __syncthreads();
      const float rD = 1.0f / D;
      {
        float hs = 0.f;
#pragma unroll
        for (int w = 0; w < 8; ++w) hs += s_hidp[w * 512 + t];
        s_out[t] = hs * rD;
      }
      float sc = 0.f; bool valid = false;
      if (t < 256) {
        valid = (s_maskP[t] != 0.f);
        sc = s_sc[t];
        float alpha = valid ? exp2f((sc - M) * L2E) * rD : 0.f;
        out[OUT_ALPHA + ((size_t)b * 256 + step) * 256 + t] = alpha;
        float bs = valid ? sc : -INFINITY;
        int bi = t;
#pragma unroll
        for (int off = 32; off > 0; off >>= 1) {
          float os = __shfl_down(bs, off);
          int oi = __shfl_down(bi, off);
          if (os > bs || (os == bs && oi < bi)) { bs = os; bi = oi; }
        }
        if ((t & 63) == 0) { s_red[t >> 6] = bs; s_redi[t >> 6] = bi; }
      }
      __syncthreads();
      if (t == 0) {
        float mm = s_red[0]; int mi = s_redi[0];
#pragma unroll
        for (int w = 1; w < 4; ++w) {
          if (s_red[w] > mm || (s_red[w] == mm && s_redi[w] < mi)) { mm = s_red[w]; mi = s_redi[w]; }
        }
        s_mi = mi;
      }
      __syncthreads();
      const int mi = s_mi;
      if (t < 128) {
        f4 hv = *(const f4*)&s_out[t * 4];
        float* hp = ws + WS_HID + (size_t)b * 512 + t * 4;
        CST4_1(hp, hv);
      }
      if (t < 64) {
        float4 xv = *(const float4*)&emb[((size_t)b * 256 + mi) * 256 + t * 4];
        f4 xq; xq[0] = xv.x; xq[1] = xv.y; xq[2] = xv.z; xq[3] = xv.w;
        float* xp = ws + WS_XT + (size_t)b * 256 + t * 4;
        CST4_1(xp, xq);
      }
      if (t == 0) {
        out[OUT_PTR + (size_t)b * 256 + step] = (float)mi;
        s_maskP[mi] = 0.f;
      }
    }
    ++tgt; gbar(flags, tgt);

    // ======== PH: h_new = tanh(Wout@[hid;ht]+bout); XCD owns 2 r-tiles; 16 b-tiles(8) ========
    {
      const int rt = (bid & 7) * 2 + ((bid >> 3) & 1);
      const int bt = bid >> 4;
      const int r0 = rt * 32, b0 = bt * 8;
      float* sh = s_act;               // [8][1028]
      float* stmp = s_act + 8224;      // [8][33]
      f4 va[4]; const float* pa[4];
#pragma unroll
      for (int it = 0; it < 4; ++it) {
        int c = t + it * 512;
        int bl = c >> 8, kq = c & 255;
        int kg = kq * 4;
        pa[it] = (kg < 512) ? ws + WS_HID + (size_t)(b0 + bl) * 512 + kg
                            : ws + WS_HT + (size_t)(b0 + bl) * 512 + (kg - 512);
      }
      CLD4(va, pa);
      __builtin_amdgcn_sched_barrier(0);
#pragma unroll
      for (int it = 0; it < 4; ++it) {
        int c = t + it * 512;
        int bl = c >> 8, kq = c & 255;
        *(f4*)&sh[bl * 1028 + kq * 4] = va[it];
      }
      __syncthreads();
      if (t < 256) {
        const int rl = t >> 3, bb = t & 7;
        const float* w = Wout + (size_t)(r0 + rl) * 1024;
        const float* sa = sh + bb * 1028;
        float acc = 0.f;
#pragma unroll 8
        for (int k4 = 0; k4 < 256; ++k4) {
          float4 ww = *(const float4*)&w[k4 * 4];
          float4 xx = *(const float4*)&sa[k4 * 4];
          acc += ww.x * xx.x + ww.y * xx.y + ww.z * xx.z + ww.w * xx.w;
        }
        float h = ftanh(acc + bout[r0 + rl]);
        stmp[bb * 33 + rl] = h;
        if (step == L - 1) out[OUT_H + (size_t)(b0 + bb) * 512 + r0 + rl] = h;
      }
      __syncthreads();
      if (t < 64) {
        const int bb = t >> 3, q = t & 7;
        f4 v;
        v[0] = stmp[bb * 33 + q * 4 + 0];
        v[1] = stmp[bb * 33 + q * 4 + 1];
        v[2] = stmp[bb * 33 + q * 4 + 2];
        v[3] = stmp[bb * 33 + q * 4 + 3];
        float* p = ws + WS_HH + (size_t)(b0 + bb) * 512 + r0 + q * 4;
        CST4_1(p, v);
      }
    }
    ++tgt; gbar(flags, tgt);
  }
}

extern "C" void kernel_launch(void* const* d_in, const int* in_sizes, int n_in,
                              void* d_out, int out_size, void* d_ws, size_t ws_size,
                              hipStream_t stream) {
  (void)in_sizes; (void)n_in; (void)out_size; (void)ws_size;
  const float* emb    = (const float*)d_in[0];
  const float* dec_in = (const float*)d_in[1];
  const float* dec_h  = (const float*)d_in[2];
  const float* dec_c  = (const float*)d_in[3];
  const float* ctx_in = (const float*)d_in[4];
  const float* W_i2h  = (const float*)d_in[5];
  const float* b_i2h  = (const float*)d_in[6];
  const float* W_h2h  = (const float*)d_in[7];
  const float* b_h2h  = (const float*)d_in[8];
  const float* W_out  = (const float*)d_in[9];
  const float* b_out  = (const float*)d_in[10];
  const float* W_inp  = (const float*)d_in[11];
  const float* b_inp  = (const float*)d_in[12];
  const float* W_ctx  = (const float*)d_in[13];
  const float* b_ctx  = (const float*)d_in[14];
  const float* Vv     = (const float*)d_in[15];
  float* out = (float*)d_out;
  float* ws  = (float*)d_ws;

  k_ctx<<<dim3(512, 8), 256, 0, stream>>>(ctx_in, W_ctx, b_ctx, ws);
  k_init<<<401, 256, 0, stream>>>(dec_h, dec_in, ws);
  k_main<<<NBLK, NTHR, 0, stream>>>(W_i2h, b_i2h, W_h2h, b_h2h, W_out, b_out,
                                    W_inp, b_inp, Vv, emb, dec_c, ws, out);
}